// Round 11
// baseline (466.749 us; speedup 1.0000x reference)
//
#include <hip/hip_runtime.h>

// LSTM rollout B=1024,S=128,H=256,glen=32. 256 blocks x 512 thr (8 waves),
// 1 block/CU (LDS-limited), 4 batches/block, zero inter-block comm.
// W_hh fp16 fragments: tk0-3 in VGPRs (128/lane), tk4-5 in LDS (128KB),
// tk6-7 streamed from L2 (128KB/step). Replicated-row MFMA: C reg r =
// batch r on every lane -> cndmask select, full-wave nonlinearity.
// R10 change vs R9: fix 128-VGPR spill (launch_bounds(512,2) acted as
// min-2-blocks/CU -> 128 cap, 24MB scratch writes). Now
// amdgpu_waves_per_eu(2) (256 cap) + dropped bgA cross-barrier prefetch
// (-32 live regs) -> peak demand ~236, no spill.
// (Resubmission: round-10 bench failed on infra before compile.)

#define SEQ 128
#define HID 256
#define GLEN 32
#define NB  256
#define NT  512

typedef _Float16 f16;
typedef _Float16 half8 __attribute__((ext_vector_type(8)));
typedef float floatx4 __attribute__((ext_vector_type(4)));
typedef float floatx2 __attribute__((ext_vector_type(2)));

#define OFF_REG   0u
#define OFF_LDSF  (256u << 10)
#define OFF_L2F   (384u << 10)
#define OFF_COMBO (512u << 10)

__device__ __forceinline__ float sigf(float x) {
  return __builtin_amdgcn_rcpf(1.0f + __builtin_amdgcn_exp2f(-1.44269504088896341f * x));
}
__device__ __forceinline__ float tanhf_(float x) {
  float e = __builtin_amdgcn_exp2f(2.88539008177792681f * x);
  return 1.0f - 2.0f * __builtin_amdgcn_rcpf(e + 1.0f);
}
// reduce over the 16-lane DPP row via rotate-add; every lane ends with the row sum
#define RORADD(v, C) { int _t = __builtin_amdgcn_update_dpp(0, __float_as_int(v), (C), 0xF, 0xF, true); (v) += __int_as_float(_t); }

// ---------------- prep: W_hh fp32 -> fp16 MFMA B-fragments ----------------
__global__ void lstm_prep(const float* __restrict__ W_ih, const float* __restrict__ W_hh,
                          const float* __restrict__ b_ih, const float* __restrict__ b_hh,
                          char* __restrict__ ws) {
  const int blk = blockIdx.x, tid = threadIdx.x;
  if (blk < 128) {
    const int gid = blk * 256 + tid;
    const int F = gid >> 6, lane = gid & 63;
    int tn, tk; unsigned dst;
    if (F < 256) {          // reg frags: F = wv*32 + U*16 + q*4 + tk
      int wv = F >> 5, U = (F >> 4) & 1, q = (F >> 2) & 3; tk = F & 3;
      tn = q * 16 + U * 8 + wv; dst = OFF_REG + (unsigned)F * 1024;
    } else if (F < 384) {   // LDS frags: tk 4,5
      int F2 = F - 256; tn = F2 >> 1; tk = 4 + (F2 & 1); dst = OFF_LDSF + (unsigned)F2 * 1024;
    } else {                // L2-streamed frags: tk 6,7
      int F3 = F - 384; tn = F3 >> 1; tk = 6 + (F3 & 1); dst = OFF_L2F + (unsigned)F3 * 1024;
    }
    const int row = tn * 16 + (lane & 15);
    const int k0 = tk * 32 + (lane >> 4) * 8;
    const float* src = W_hh + row * HID + k0;
    half8 hv;
#pragma unroll
    for (int j = 0; j < 8; ++j) hv[j] = (f16)src[j];
    *(half8*)(ws + dst + lane * 16) = hv;
  } else {
    for (int r = tid; r < 4 * HID; r += 256) {
      floatx2 cw; cw[0] = W_ih[r]; cw[1] = b_ih[r] + b_hh[r];
      *(floatx2*)(ws + OFF_COMBO + (unsigned)r * 8) = cw;
    }
  }
}

// ---------------- main ----------------------------------------------------
__global__ __launch_bounds__(NT) __attribute__((amdgpu_waves_per_eu(2)))
void lstm_main(const float* __restrict__ prefix, const float* __restrict__ W_out,
               const float* __restrict__ b_out, const char* __restrict__ ws,
               float* __restrict__ out) {
  __shared__ __align__(16) char fragL[131072];   // tk4,5 fragments
  __shared__ __align__(16) char hbuf[2048];      // h fp16 [4 b][256 u], ^(b<<5)
  __shared__ __align__(16) floatx2 comboL[1024]; // per-row {W_ih, b_ih+b_hh}
  __shared__ float woutL[HID];
  __shared__ float pwarm[4][32];
  __shared__ float ypart[4][8];
  __shared__ float xfin[4];

  const int tid = threadIdx.x;
  const int lane = tid & 63;
  const int wv = tid >> 6;       // 0..7
  const int m15 = lane & 15;
  const int hi4 = lane >> 4;     // 0..3 = owned batch
  const int bbase = blockIdx.x * 4;

  for (int i = tid; i < 8192; i += NT)
    *(int4*)(fragL + i * 16) = *(const int4*)(ws + OFF_LDSF + i * 16);
  for (int i = tid; i < 1024; i += NT)
    comboL[i] = *(const floatx2*)(ws + OFF_COMBO + i * 8);
  if (tid < HID) woutL[tid] = W_out[tid];
  if (tid < 128) {
    int b = tid >> 5, t = tid & 31;
    float v = prefix[(bbase + b) * SEQ + t];
    pwarm[b][t] = v;
    out[(bbase + b) * SEQ + t] = v;   // prefix part of output
  }
  if (tid < 4) xfin[tid] = prefix[(bbase + tid) * SEQ];
  if (tid < 128) { int4 z = {0, 0, 0, 0}; *(int4*)(hbuf + tid * 16) = z; }
  const float bout = b_out[0];

  half8 wreg[2][4][4];   // [U][q][tk0-3]
  {
    const char* rb = ws + OFF_REG + (unsigned)wv * 32768 + (unsigned)lane * 16;
#pragma unroll
    for (int U = 0; U < 2; ++U)
#pragma unroll
      for (int q = 0; q < 4; ++q)
#pragma unroll
        for (int tk = 0; tk < 4; ++tk)
          wreg[U][q][tk] = *(const half8*)(rb + (unsigned)((U * 16 + q * 4 + tk) * 1024));
  }
  float cst[2] = {0.f, 0.f};
  const int bb = m15 & 3;
  const bool c1 = (hi4 == 1), c2 = (hi4 == 2), c3 = (hi4 == 3);

  __syncthreads();

#pragma unroll 1
  for (int s = 0; s < SEQ; ++s) {
    // A-fragments of h^s (rows replicated: row m <- batch m&3)
    half8 afrag[8];
#pragma unroll
    for (int tk = 0; tk < 8; ++tk)
      afrag[tk] = *(const half8*)(hbuf + ((bb * 512 + tk * 64 + hi4 * 16) ^ (bb << 5)));
    __syncthreads();   // B1: afrag reads done -> hbuf/xfin writable
    const float xv = xfin[hi4];
    float py = 0.f;

#pragma unroll
    for (int U = 0; U < 2; ++U) {
      const int Ug = U * 8 + wv;
      // L2-streamed tk6,7 fragments: issue all 8 loads first (used at the
      // tail of each q-chain, ~8 MFMAs + LDS reads of cover + 2 waves/SIMD)
      half8 bg[4][2];
#pragma unroll
      for (int q = 0; q < 4; ++q) {
        const char* p = ws + OFF_L2F + (unsigned)((q * 16 + Ug) * 2) * 1024 + (unsigned)lane * 16;
        bg[q][0] = *(const half8*)p;
        bg[q][1] = *(const half8*)(p + 1024);
      }
      floatx2 cw[4];
#pragma unroll
      for (int q = 0; q < 4; ++q) cw[q] = comboL[(q * 16 + Ug) * 16 + m15];
      floatx4 ac[4];
#pragma unroll
      for (int q = 0; q < 4; ++q) ac[q] = (floatx4){0.f, 0.f, 0.f, 0.f};
      // LDS frags with 1-q lookahead
      half8 nb0, nb1;
      {
        const char* p = fragL + (unsigned)((0 * 16 + Ug) * 2) * 1024 + (unsigned)lane * 16;
        nb0 = *(const half8*)p; nb1 = *(const half8*)(p + 1024);
      }
#pragma unroll
      for (int q = 0; q < 4; ++q) {
        half8 b0 = nb0, b1 = nb1;
        if (q < 3) {
          const char* p = fragL + (unsigned)(((q + 1) * 16 + Ug) * 2) * 1024 + (unsigned)lane * 16;
          nb0 = *(const half8*)p; nb1 = *(const half8*)(p + 1024);
        }
        ac[q] = __builtin_amdgcn_mfma_f32_16x16x32_f16(afrag[0], wreg[U][q][0], ac[q], 0, 0, 0);
        ac[q] = __builtin_amdgcn_mfma_f32_16x16x32_f16(afrag[1], wreg[U][q][1], ac[q], 0, 0, 0);
        ac[q] = __builtin_amdgcn_mfma_f32_16x16x32_f16(afrag[2], wreg[U][q][2], ac[q], 0, 0, 0);
        ac[q] = __builtin_amdgcn_mfma_f32_16x16x32_f16(afrag[3], wreg[U][q][3], ac[q], 0, 0, 0);
        ac[q] = __builtin_amdgcn_mfma_f32_16x16x32_f16(afrag[4], b0, ac[q], 0, 0, 0);
        ac[q] = __builtin_amdgcn_mfma_f32_16x16x32_f16(afrag[5], b1, ac[q], 0, 0, 0);
        ac[q] = __builtin_amdgcn_mfma_f32_16x16x32_f16(afrag[6], bg[q][0], ac[q], 0, 0, 0);
        ac[q] = __builtin_amdgcn_mfma_f32_16x16x32_f16(afrag[7], bg[q][1], ac[q], 0, 0, 0);
      }
      // row r of C = batch r (replicated A) -> select own batch hi4, in-lane
      float g[4];
#pragma unroll
      for (int q = 0; q < 4; ++q) {
        float v = ac[q][0];
        v = c1 ? ac[q][1] : v;
        v = c2 ? ac[q][2] : v;
        v = c3 ? ac[q][3] : v;
        g[q] = v;
      }
      float pi = g[0] + __builtin_fmaf(xv, cw[0][0], cw[0][1]);
      float pf = g[1] + __builtin_fmaf(xv, cw[1][0], cw[1][1]);
      float pg = g[2] + __builtin_fmaf(xv, cw[2][0], cw[2][1]);
      float po = g[3] + __builtin_fmaf(xv, cw[3][0], cw[3][1]);
      float cn = __builtin_fmaf(sigf(pf), cst[U], sigf(pi) * tanhf_(pg));
      cst[U] = cn;
      float hn = sigf(po) * tanhf_(cn);
      const int u = Ug * 16 + m15;
      *(f16*)(hbuf + ((hi4 * 512 + u * 2) ^ (hi4 << 5))) = (f16)hn;
      if (s >= GLEN) py = __builtin_fmaf(hn, woutL[u], py);
    }

    if (s >= GLEN) {   // y partials: reduce over the 16-lane row (units)
      RORADD(py, 0x121); RORADD(py, 0x122); RORADD(py, 0x124); RORADD(py, 0x128);
      if (m15 == 0) ypart[hi4][wv] = py;
    }
    __syncthreads();   // B2: h^{s+1} + ypart complete
    if (wv == 0) {
      if (s >= GLEN) {
        float v = ((const float*)ypart)[lane & 31];   // [b=L>>3][wv=L&7]
        v += __shfl_xor(v, 1);
        v += __shfl_xor(v, 2);
        v += __shfl_xor(v, 4);
        if (lane < 32 && (lane & 7) == 0) {
          const int b = lane >> 3;
          const float y = v + bout;
          out[(bbase + b) * SEQ + s] = y;
          xfin[b] = y;               // autoregressive feed
        }
      } else {
        if (lane < 4) {
          const int idx = (s + 1 < GLEN) ? (s + 1) : (GLEN - 1);
          xfin[lane] = pwarm[lane][idx];
        }
      }
    }
  }
}

extern "C" void kernel_launch(void* const* d_in, const int* in_sizes, int n_in,
                              void* d_out, int out_size, void* d_ws, size_t ws_size,
                              hipStream_t stream) {
  const float* prefix = (const float*)d_in[0];
  const float* W_ih   = (const float*)d_in[1];
  const float* W_hh   = (const float*)d_in[2];
  const float* b_ih   = (const float*)d_in[3];
  const float* b_hh   = (const float*)d_in[4];
  const float* W_out  = (const float*)d_in[5];
  const float* b_out  = (const float*)d_in[6];
  float* out = (float*)d_out;
  char* ws = (char*)d_ws;

  lstm_prep<<<dim3(129), dim3(256), 0, stream>>>(W_ih, W_hh, b_ih, b_hh, ws);
  lstm_main<<<dim3(NB), dim3(NT), 0, stream>>>(prefix, W_out, b_out, ws, out);
}